// Round 4
// baseline (1330.571 us; speedup 1.0000x reference)
//
#include <hip/hip_runtime.h>
#include <cstddef>

#define TT   32
#define NN   256
#define NLL  16
#define HH   256
#define CONDD 64
#define NEE  8
#define H3   768
#define OW   308

typedef __attribute__((ext_vector_type(8))) short bf16x8;
typedef __attribute__((ext_vector_type(4))) float f32x4;
typedef unsigned short u16;

__device__ __forceinline__ float sigm(float x)     { return 1.f / (1.f + __expf(-x)); }
__device__ __forceinline__ float tanhfast(float x) { return 1.f - 2.f / (__expf(2.f * x) + 1.f); }
__device__ __forceinline__ float bf2f(u16 h) {
    union { unsigned u; float f; } v; v.u = ((unsigned)h) << 16; return v.f;
}
__device__ __forceinline__ u16 f2bf(float f) {   // round-to-nearest-even
    union { float f; unsigned u; } v; v.f = f;
    unsigned r = v.u + 0x7fffu + ((v.u >> 16) & 1u);
    return (u16)(r >> 16);
}
#define MFMA(a, b, c) __builtin_amdgcn_mfma_f32_16x16x32_bf16(a, b, c, 0, 0, 0)

// ---------------------------------------------------------------------------
// fp32 -> bf16 casts
// ---------------------------------------------------------------------------
__global__ void k_cast(const float* __restrict__ s, u16* __restrict__ d, int n) {
    int i = blockIdx.x * 256 + threadIdx.x;
    if (i < n) d[i] = f2bf(s[i]);
}
// cwih (768,320) -> cond part (768,64) bf16
__global__ void k_cast_cwc(const float* __restrict__ cwih, u16* __restrict__ d) {
    int i = blockIdx.x * 256 + threadIdx.x;
    if (i < 768 * 64) { int r = i >> 6, c = i & 63; d[i] = f2bf(cwih[r * 320 + c]); }
}

// ---------------------------------------------------------------------------
// Per-token input projections (bf16 tables, biases folded in)
// ---------------------------------------------------------------------------
__global__ __launch_bounds__(256) void k_tok_gi(
    const float* __restrict__ embed,
    const float* __restrict__ gwih_f, const float* __restrict__ gbih_f,
    const float* __restrict__ gwih_b, const float* __restrict__ gbih_b,
    const float* __restrict__ cwih,   const float* __restrict__ cbih,
    u16* __restrict__ gif, u16* __restrict__ gib, u16* __restrict__ gic)
{
    int v = blockIdx.x, tid = threadIdx.x;
    __shared__ float es[256];
    es[tid] = embed[v * HH + tid];
    __syncthreads();
    for (int g = 0; g < 3; ++g) {
        int col = g * 256 + tid;
        float af = gbih_f[col], abv = gbih_b[col], ac = cbih[col];
        const float* wf = gwih_f + (size_t)col * HH;
        const float* wb = gwih_b + (size_t)col * HH;
        const float* wc = cwih   + (size_t)col * (HH + CONDD) + CONDD;
        for (int c = 0; c < 256; ++c) {
            float e = es[c];
            af += e * wf[c]; abv += e * wb[c]; ac += e * wc[c];
        }
        gif[v * H3 + col] = f2bf(af);
        gib[v * H3 + col] = f2bf(abv);
        gic[v * H3 + col] = f2bf(ac);
    }
}

// ---------------------------------------------------------------------------
// w-trajectory + out[.,.,0..2]
// ---------------------------------------------------------------------------
__global__ void k_wtraj(const int* __restrict__ actions, const int* __restrict__ w0,
                        float* __restrict__ out, int* __restrict__ w_used)
{
    int n = threadIdx.x;
    int w = w0[n];
    for (int t = 0; t < TT; ++t) {
        int A = actions[((size_t)t * NN + n) * 2 + 0];
        int W = actions[((size_t)t * NN + n) * 2 + 1];
        w_used[t * NN + n] = w;
        int wn = w + W - NLL;
        wn = wn < 0 ? 0 : (wn > NLL - 1 ? NLL - 1 : wn);
        float* o = out + ((size_t)t * NN + n) * OW;
        o[0] = (float)A; o[1] = (float)W; o[2] = (float)wn;
        w = wn;
    }
}

// ---------------------------------------------------------------------------
// MEGA persistent kernel.
//   bid < 256 : GRU role. 32 rows/block (block entirely fwd or bwd). 16 steps.
//               h kept in LDS (bf16 for MFMA A-frags, fp32 tile for B-proj).
//   bid >= 256: controller role (16 blocks x 16 batch rows). 32 steps.
//               gh = h@cwhh^T (K=256) + cond@cwihc^T (K=64) fused in MFMA acc;
//               n-gate cond part kept in separate acc (r-gating only scales gh).
// MFMA frag convention (k-permutation consistent across A and B):
//   A: m=lane&15, k elems = ks*32 + (lane>>4)*8 + e  (16B contiguous load)
//   B: n=lane&15, same k elems; B[k][n] = Wrowmajor[n][k] -> 16B contiguous
//   C: col=lane&15, row=(lane>>4)*4+reg   (m89-verified)
// ---------------------------------------------------------------------------
__global__ __launch_bounds__(512) void k_mega(
    const u16* __restrict__ whhbf_f, const u16* __restrict__ whhbf_b,
    const u16* __restrict__ gif, const u16* __restrict__ gib,
    const float* __restrict__ gbhh_f, const float* __restrict__ gbhh_b,
    const float* __restrict__ w2, const float* __restrict__ b2,
    float* __restrict__ Bf, float* __restrict__ Bb,
    const int* __restrict__ lines,
    const u16* __restrict__ cwhhbf, const u16* __restrict__ cwcbf,
    const u16* __restrict__ condbf, const u16* __restrict__ gic,
    const float* __restrict__ cbhh, const float* __restrict__ h0,
    const int* __restrict__ w_used,
    u16* __restrict__ Hallbf, float* __restrict__ out)
{
    __shared__ __align__(16) char smem[51968];
    const int bid  = blockIdx.x;
    const int tid  = threadIdx.x;
    const int lane = tid & 63;
    const int lm   = lane & 15, lg = lane >> 4;

    if (bid < 256) {
        // ---------------- GRU role ----------------
        u16*   hbf  = (u16*)smem;                       // [32][264] bf16
        float* hf32 = (float*)(smem + 16896);           // [32][258] f32
        int*   lns  = (int*)(smem + 16896 + 33024);     // [32][16]
        const int dir = bid >> 7;
        const int lb  = bid & 127;
        const int ii  = lb >> 3;
        const int nb  = (lb & 7) * 32;
        const u16*   whh  = dir ? whhbf_b : whhbf_f;
        const u16*   git  = dir ? gib : gif;
        const float* bhh  = dir ? gbhh_b : gbhh_f;
        float*       Bout = dir ? Bb : Bf;
        const int w = tid >> 6;   // wave 0..7, owns cols w*32..w*32+31 per chunk

        for (int k = tid; k < 32 * 264; k += 512) hbf[k] = 0;
        { int r = tid >> 4, c = tid & 15; lns[r * 16 + c] = lines[(nb + r) * 16 + c]; }
        __syncthreads();

        for (int s = 0; s < 16; ++s) {
            const int jpos = dir ? (15 - s) : s;
            f32x4 acc[3][2][2];
            #pragma unroll
            for (int q = 0; q < 3; ++q)
                #pragma unroll
                for (int c = 0; c < 2; ++c)
                    #pragma unroll
                    for (int r = 0; r < 2; ++r)
                        #pragma unroll
                        for (int z = 0; z < 4; ++z) acc[q][c][r][z] = 0.f;

            #pragma unroll
            for (int ks = 0; ks < 8; ++ks) {
                bf16x8 a0 = *(const bf16x8*)&hbf[lm * 264 + ks * 32 + lg * 8];
                bf16x8 a1 = *(const bf16x8*)&hbf[(16 + lm) * 264 + ks * 32 + lg * 8];
                #pragma unroll
                for (int q = 0; q < 3; ++q)
                    #pragma unroll
                    for (int cf = 0; cf < 2; ++cf) {
                        const u16* bp = whh + (size_t)(q * 256 + w * 32 + cf * 16 + lm) * 256
                                        + ks * 32 + lg * 8;
                        bf16x8 b = *(const bf16x8*)bp;
                        acc[q][cf][0] = MFMA(a0, b, acc[q][cf][0]);
                        acc[q][cf][1] = MFMA(a1, b, acc[q][cf][1]);
                    }
            }
            // gates -> hf32 tile
            #pragma unroll
            for (int cf = 0; cf < 2; ++cf) {
                int col = w * 32 + cf * 16 + lm;
                float br = bhh[col], bz = bhh[col + 256], bn = bhh[col + 512];
                #pragma unroll
                for (int rf = 0; rf < 2; ++rf)
                    #pragma unroll
                    for (int j = 0; j < 4; ++j) {
                        int lrow = rf * 16 + lg * 4 + j;
                        int tok  = lns[lrow * 16 + ((ii + jpos) & 15)];
                        const u16* gi = git + (size_t)tok * H3;
                        float ho = bf2f(hbf[lrow * 264 + col]);
                        float rg = sigm(bf2f(gi[col])       + acc[0][cf][rf][j] + br);
                        float zg = sigm(bf2f(gi[col + 256]) + acc[1][cf][rf][j] + bz);
                        float ng = tanhfast(bf2f(gi[col + 512]) + rg * (acc[2][cf][rf][j] + bn));
                        hf32[lrow * 258 + col] = (1.f - zg) * ng + zg * ho;
                    }
            }
            __syncthreads();
            // hbf <- bf16(hf32)
            {
                int lrow = tid >> 4, c0 = (tid & 15) * 16;
                u16 tmp[16];
                #pragma unroll
                for (int k = 0; k < 16; ++k) tmp[k] = f2bf(hf32[lrow * 258 + c0 + k]);
                *(uint4*)&hbf[lrow * 264 + c0]     = *(uint4*)&tmp[0];
                *(uint4*)&hbf[lrow * 264 + c0 + 8] = *(uint4*)&tmp[8];
            }
            // fused B projection (fp32 h)
            if (tid < 256) {
                int r = tid >> 3, e = tid & 7;
                float a = b2[e];
                const float* w2r = w2 + e * 256;
                for (int c = 0; c < 256; ++c) a += hf32[r * 258 + c] * w2r[c];
                int grow = ii * 256 + nb + r;
                Bout[((size_t)grow * NLL + jpos) * NEE + e] = sigm(a);
            }
            __syncthreads();
        }
    } else {
        // ---------------- controller role ----------------
        u16* hc = (u16*)smem;            // [16][264] bf16
        const int cb = bid - 256;        // 0..15, rows cb*16..cb*16+15
        if (tid < 256) {
            int lrow = tid >> 4, c0 = (tid & 15) * 16;
            u16 tmp[16];
            #pragma unroll
            for (int k = 0; k < 16; ++k)
                tmp[k] = f2bf(h0[(size_t)(cb * 16 + lrow) * 256 + c0 + k]);
            *(uint4*)&hc[lrow * 264 + c0]     = *(uint4*)&tmp[0];
            *(uint4*)&hc[lrow * 264 + c0 + 8] = *(uint4*)&tmp[8];
        }
        __syncthreads();
        const int w = tid >> 6;  // 0..3 for active threads

        for (int t = 0; t < TT; ++t) {
            f32x4 accM[3][4], accC[4];
            if (tid < 256) {
                #pragma unroll
                for (int q = 0; q < 3; ++q)
                    #pragma unroll
                    for (int c = 0; c < 4; ++c)
                        #pragma unroll
                        for (int z = 0; z < 4; ++z) accM[q][c][z] = 0.f;
                #pragma unroll
                for (int c = 0; c < 4; ++c)
                    #pragma unroll
                    for (int z = 0; z < 4; ++z) accC[c][z] = 0.f;

                // h @ cwhh^T  (K=256)
                #pragma unroll
                for (int ks = 0; ks < 8; ++ks) {
                    bf16x8 a = *(const bf16x8*)&hc[lm * 264 + ks * 32 + lg * 8];
                    #pragma unroll
                    for (int q = 0; q < 3; ++q)
                        #pragma unroll
                        for (int cf = 0; cf < 4; ++cf) {
                            const u16* bp = cwhhbf + (size_t)(q * 256 + w * 64 + cf * 16 + lm) * 256
                                            + ks * 32 + lg * 8;
                            accM[q][cf] = MFMA(a, *(const bf16x8*)bp, accM[q][cf]);
                        }
                }
                // cond @ cwih_cond^T  (K=64); chunks r,z merge; n-chunk separate
                #pragma unroll
                for (int ks = 0; ks < 2; ++ks) {
                    bf16x8 a = *(const bf16x8*)&condbf[(size_t)(t * 256 + cb * 16 + lm) * 64
                                                       + ks * 32 + lg * 8];
                    #pragma unroll
                    for (int q = 0; q < 3; ++q)
                        #pragma unroll
                        for (int cf = 0; cf < 4; ++cf) {
                            const u16* bp = cwcbf + (size_t)(q * 256 + w * 64 + cf * 16 + lm) * 64
                                            + ks * 32 + lg * 8;
                            bf16x8 b = *(const bf16x8*)bp;
                            if (q < 2) accM[q][cf] = MFMA(a, b, accM[q][cf]);
                            else       accC[cf]    = MFMA(a, b, accC[cf]);
                        }
                }
            }
            __syncthreads();   // all hc reads complete
            if (tid < 256) {
                #pragma unroll
                for (int cf = 0; cf < 4; ++cf) {
                    int col = w * 64 + cf * 16 + lm;
                    float br = cbhh[col], bz = cbhh[col + 256], bn = cbhh[col + 512];
                    #pragma unroll
                    for (int j = 0; j < 4; ++j) {
                        int lrow = lg * 4 + j;
                        int n = cb * 16 + lrow;
                        int wv = w_used[t * 256 + n];
                        int tok = lines[n * 16 + wv];
                        const u16* gi = gic + (size_t)tok * H3;
                        float ho = bf2f(hc[lrow * 264 + col]);
                        float rg = sigm(bf2f(gi[col])       + accM[0][cf][j] + br);
                        float zg = sigm(bf2f(gi[col + 256]) + accM[1][cf][j] + bz);
                        float ng = tanhfast(bf2f(gi[col + 512]) + accC[cf][j]
                                            + rg * (accM[2][cf][j] + bn));
                        float hn = (1.f - zg) * ng + zg * ho;
                        out[((size_t)t * 256 + n) * OW + 4 + col] = hn;
                        Hallbf[((size_t)t * 256 + n) * 256 + col] = f2bf(hn);
                        hc[lrow * 264 + col] = f2bf(hn);   // same-element RAW: own read done
                    }
                }
            }
            __syncthreads();   // hc ready for next step
        }
    }
}

// ---------------------------------------------------------------------------
// Stick-breaking + reversals + roll into final P layout (unchanged, verified)
// ---------------------------------------------------------------------------
__global__ __launch_bounds__(256) void k_stick(
    const float* __restrict__ Bf, const float* __restrict__ Bb,
    float* __restrict__ P_final)
{
    int idx = blockIdx.x * 256 + threadIdx.x;
    if (idx >= 16 * 256 * 8) return;
    int e = idx & 7, n = (idx >> 3) & 255, i = idx >> 11;
    const float* bf = Bf + ((size_t)(i * NN + n) * NLL) * NEE + e;
    const float* bb = Bb + ((size_t)(i * NN + n) * NLL) * NEE + e;
    int i2 = (i + 15) & 15;
    float* dst = P_final + ((size_t)(i2 * NN + n) * 32) * NEE + e;
    float cum = 1.f;
    #pragma unroll
    for (int m = 0; m < 16; ++m) {
        float c0 = bf[m * NEE];
        float c1 = bb[(15 - m) * NEE];
        float v0 = c0 * cum;
        cum *= (1.f - c0);
        float v1 = (m < 15) ? c1 * cum : cum;
        cum *= (1.f - c1);
        dst[(size_t)(((17 + m) & 31)) * NEE] = v0;
        dst[(size_t)((16 - m)) * NEE]        = v1;
    }
}

// ---------------------------------------------------------------------------
// Batched MLP layer: Out = bf16(relu(A @ W^T + bias)), A (8192,256) bf16
// ---------------------------------------------------------------------------
__global__ __launch_bounds__(256) void k_mlp(
    const u16* __restrict__ A, const u16* __restrict__ W,
    const float* __restrict__ bias, u16* __restrict__ Out)
{
    __shared__ u16 ot[32 * 264];
    const int g0 = blockIdx.x * 32;
    const int tid = threadIdx.x, lane = tid & 63, w = tid >> 6;
    const int lm = lane & 15, lg = lane >> 4;
    f32x4 acc[4][2];
    #pragma unroll
    for (int c = 0; c < 4; ++c)
        #pragma unroll
        for (int r = 0; r < 2; ++r)
            #pragma unroll
            for (int z = 0; z < 4; ++z) acc[c][r][z] = 0.f;
    #pragma unroll
    for (int ks = 0; ks < 8; ++ks) {
        bf16x8 a0 = *(const bf16x8*)&A[(size_t)(g0 + lm) * 256 + ks * 32 + lg * 8];
        bf16x8 a1 = *(const bf16x8*)&A[(size_t)(g0 + 16 + lm) * 256 + ks * 32 + lg * 8];
        #pragma unroll
        for (int cf = 0; cf < 4; ++cf) {
            const u16* bp = W + (size_t)(w * 64 + cf * 16 + lm) * 256 + ks * 32 + lg * 8;
            bf16x8 b = *(const bf16x8*)bp;
            acc[cf][0] = MFMA(a0, b, acc[cf][0]);
            acc[cf][1] = MFMA(a1, b, acc[cf][1]);
        }
    }
    #pragma unroll
    for (int cf = 0; cf < 4; ++cf) {
        int col = w * 64 + cf * 16 + lm;
        float bs = bias[col];
        #pragma unroll
        for (int rf = 0; rf < 2; ++rf)
            #pragma unroll
            for (int j = 0; j < 4; ++j) {
                int lrow = rf * 16 + lg * 4 + j;
                ot[lrow * 264 + col] = f2bf(fmaxf(acc[cf][rf][j] + bs, 0.f));
            }
    }
    __syncthreads();
    int lrow = tid >> 3, c0 = (tid & 7) * 32;
    const uint4* src = (const uint4*)&ot[lrow * 264 + c0];
    uint4* dst = (uint4*)&Out[(size_t)(g0 + lrow) * 256 + c0];
    dst[0] = src[0]; dst[1] = src[1]; dst[2] = src[2]; dst[3] = src[3];
}

// ---------------------------------------------------------------------------
// Heads: 25 logits per row + softmaxes + v + p_probs, writes out cols 3,260..307
// ---------------------------------------------------------------------------
__global__ __launch_bounds__(256) void k_heads(
    const u16* __restrict__ zbf,
    const float* __restrict__ aw, const float* __restrict__ ab,
    const float* __restrict__ ow, const float* __restrict__ ob,
    const float* __restrict__ cw, const float* __restrict__ cb,
    const float* __restrict__ P_final, const int* __restrict__ w_used,
    float* __restrict__ out)
{
    __shared__ float zt[32 * 258];
    __shared__ float hd[32][28];
    __shared__ float o8[32][8];
    __shared__ int   wv[32];
    const int g0 = blockIdx.x * 32, tid = threadIdx.x;
    {
        int lrow = tid >> 3, c0 = (tid & 7) * 32;
        const u16* src = &zbf[(size_t)(g0 + lrow) * 256 + c0];
        #pragma unroll
        for (int k = 0; k < 32; ++k) zt[lrow * 258 + c0 + k] = bf2f(src[k]);
    }
    if (tid < 32) wv[tid] = w_used[g0 + tid];
    __syncthreads();
    {
        int r = tid >> 3, s = tid & 7;
        const float* z = &zt[r * 258];
        float a1 = ab[s], a2 = ab[8 + s], a3 = ob[s], a4 = cb[0];
        const float* w1 = aw + s * 256;
        const float* w2_ = aw + (8 + s) * 256;
        const float* w3 = ow + s * 256;
        for (int c = 0; c < 256; ++c) {
            float zv = z[c];
            a1 += zv * w1[c]; a2 += zv * w2_[c]; a3 += zv * w3[c]; a4 += zv * cw[c];
        }
        hd[r][s] = a1; hd[r][8 + s] = a2; hd[r][16 + s] = a3;
        if (s == 0) hd[r][24] = a4;
    }
    __syncthreads();
    if (tid < 32) {
        int r = tid; int g = g0 + r;
        float* orow = out + (size_t)g * OW;
        float mx = hd[r][0];
        #pragma unroll
        for (int k = 1; k < 16; ++k) mx = fmaxf(mx, hd[r][k]);
        float ex[16], ssum = 0.f;
        #pragma unroll
        for (int k = 0; k < 16; ++k) { ex[k] = __expf(hd[r][k] - mx); ssum += ex[k]; }
        float inv = 1.f / ssum;
        #pragma unroll
        for (int k = 0; k < 16; ++k) orow[260 + k] = ex[k] * inv;
        orow[3] = hd[r][24];
        float mo = hd[r][16];
        #pragma unroll
        for (int k = 1; k < 8; ++k) mo = fmaxf(mo, hd[r][16 + k]);
        float eo[8], so = 0.f;
        #pragma unroll
        for (int k = 0; k < 8; ++k) { eo[k] = __expf(hd[r][16 + k] - mo); so += eo[k]; }
        float invo = 1.f / so;
        #pragma unroll
        for (int k = 0; k < 8; ++k) o8[r][k] = eo[k] * invo;
    }
    __syncthreads();
    {
        int r = tid >> 3, kb = tid & 7;
        int g = g0 + r, n = g & 255;
        const float* base = P_final + ((size_t)(wv[r] * NN + n) * 32) * NEE;
        float* orow = out + (size_t)g * OW + 276;
        #pragma unroll
        for (int m = 0; m < 4; ++m) {
            int k = kb + m * 8;
            const float* pe = base + k * NEE;
            float a = 0.f;
            #pragma unroll
            for (int e = 0; e < 8; ++e) a += pe[e] * o8[r][e];
            orow[k] = a;
        }
    }
}

// ---------------------------------------------------------------------------
extern "C" void kernel_launch(void* const* d_in, const int* in_sizes, int n_in,
                              void* d_out, int out_size, void* d_ws, size_t ws_size,
                              hipStream_t stream) {
    const float* condition = (const float*)d_in[0];
    const int*   lines     = (const int*)  d_in[1];
    const int*   actions   = (const int*)  d_in[2];
    const float* h0        = (const float*)d_in[3];
    const int*   w0        = (const int*)  d_in[4];
    const float* embed     = (const float*)d_in[5];
    const float* gwih_f    = (const float*)d_in[6];
    const float* gwhh_f    = (const float*)d_in[7];
    const float* gbih_f    = (const float*)d_in[8];
    const float* gbhh_f    = (const float*)d_in[9];
    const float* gwih_b    = (const float*)d_in[10];
    const float* gwhh_b    = (const float*)d_in[11];
    const float* gbih_b    = (const float*)d_in[12];
    const float* gbhh_b    = (const float*)d_in[13];
    const float* w2        = (const float*)d_in[14];
    const float* b2        = (const float*)d_in[15];
    const float* cwih      = (const float*)d_in[16];
    const float* cwhh      = (const float*)d_in[17];
    const float* cbih      = (const float*)d_in[18];
    const float* cbhh      = (const float*)d_in[19];
    const float* mw1       = (const float*)d_in[20];
    const float* mb1       = (const float*)d_in[21];
    const float* mw2       = (const float*)d_in[22];
    const float* mb2       = (const float*)d_in[23];
    const float* ow        = (const float*)d_in[24];
    const float* ob        = (const float*)d_in[25];
    const float* aw        = (const float*)d_in[26];
    const float* ab        = (const float*)d_in[27];
    const float* cw        = (const float*)d_in[28];
    const float* cb        = (const float*)d_in[29];
    float* out = (float*)d_out;

    // workspace carve-up (~19.3 MB peak, aliased)
    char* base = (char*)d_ws;
    auto alloc = [&](size_t bytes) { char* r = base; base += (bytes + 255) & ~(size_t)255; return r; };
    u16*   gif_tok = (u16*)alloc(64 * H3 * 2);
    u16*   gib_tok = (u16*)alloc(64 * H3 * 2);
    u16*   gic_tok = (u16*)alloc(64 * H3 * 2);
    u16*   whhbf_f = (u16*)alloc(H3 * 256 * 2);
    u16*   whhbf_b = (u16*)alloc(H3 * 256 * 2);
    u16*   cwhhbf  = (u16*)alloc(H3 * 256 * 2);
    u16*   mw1bf   = (u16*)alloc(256 * 256 * 2);
    u16*   mw2bf   = (u16*)alloc(256 * 256 * 2);
    u16*   cwcbf   = (u16*)alloc(H3 * 64 * 2);
    u16*   condbf  = (u16*)alloc((size_t)TT * NN * CONDD * 2);
    float* Bf      = (float*)alloc((size_t)16 * 256 * 16 * 8 * 4);   // aliased: z1bf
    float* Bb      = (float*)alloc((size_t)16 * 256 * 16 * 8 * 4);   // (contiguous w/ Bf)
    float* P_final = (float*)alloc((size_t)16 * 256 * 32 * 8 * 4);
    u16*   Hallbf  = (u16*)alloc((size_t)TT * NN * 256 * 2);
    u16*   zbf     = (u16*)alloc((size_t)TT * NN * 256 * 2);
    int*   w_used  = (int*)alloc((size_t)TT * NN * 4);
    u16*   z1bf    = (u16*)Bf;   // reuse Bf+Bb (4 MB) after k_stick

    // bf16 weight/activation conversions
    k_cast<<<(196608 + 255) / 256, 256, 0, stream>>>(gwhh_f, whhbf_f, 196608);
    k_cast<<<(196608 + 255) / 256, 256, 0, stream>>>(gwhh_b, whhbf_b, 196608);
    k_cast<<<(196608 + 255) / 256, 256, 0, stream>>>(cwhh, cwhhbf, 196608);
    k_cast<<<(65536 + 255) / 256, 256, 0, stream>>>(mw1, mw1bf, 65536);
    k_cast<<<(65536 + 255) / 256, 256, 0, stream>>>(mw2, mw2bf, 65536);
    k_cast<<<(524288 + 255) / 256, 256, 0, stream>>>(condition, condbf, 524288);
    k_cast_cwc<<<192, 256, 0, stream>>>(cwih, cwcbf);

    k_tok_gi<<<64, 256, 0, stream>>>(embed, gwih_f, gbih_f, gwih_b, gbih_b, cwih, cbih,
                                     gif_tok, gib_tok, gic_tok);
    k_wtraj<<<1, 256, 0, stream>>>(actions, w0, out, w_used);

    // GRU (256 blocks) + controller (16 blocks), persistent, concurrent
    k_mega<<<272, 512, 0, stream>>>(whhbf_f, whhbf_b, gif_tok, gib_tok, gbhh_f, gbhh_b,
                                    w2, b2, Bf, Bb, lines,
                                    cwhhbf, cwcbf, condbf, gic_tok, cbhh, h0, w_used,
                                    Hallbf, out);

    k_stick<<<128, 256, 0, stream>>>(Bf, Bb, P_final);

    k_mlp<<<256, 256, 0, stream>>>(Hallbf, mw1bf, mb1, z1bf);
    k_mlp<<<256, 256, 0, stream>>>(z1bf, mw2bf, mb2, zbf);

    k_heads<<<256, 256, 0, stream>>>(zbf, aw, ab, ow, ob, cw, cb, P_final, w_used, out);
}

// Round 5
// 727.140 us; speedup vs baseline: 1.8299x; 1.8299x over previous
//
#include <hip/hip_runtime.h>
#include <cstddef>
#include <cstdint>

#define TT   32
#define NN   256
#define NLL  16
#define HH   256
#define CONDD 64
#define NEE  8
#define H3   768
#define OW   308

typedef __attribute__((ext_vector_type(8))) short bf16x8;
typedef __attribute__((ext_vector_type(4))) float f32x4;
typedef unsigned short u16;

__device__ __forceinline__ float sigm(float x)     { return 1.f / (1.f + __expf(-x)); }
__device__ __forceinline__ float tanhfast(float x) { return 1.f - 2.f / (__expf(2.f * x) + 1.f); }
__device__ __forceinline__ float bf2f(u16 h) {
    union { unsigned u; float f; } v; v.u = ((unsigned)h) << 16; return v.f;
}
__device__ __forceinline__ u16 f2bf(float f) {   // round-to-nearest-even
    union { float f; unsigned u; } v; v.f = f;
    unsigned r = v.u + 0x7fffu + ((v.u >> 16) & 1u);
    return (u16)(r >> 16);
}
#define MFMA(a, b, c) __builtin_amdgcn_mfma_f32_16x16x32_bf16(a, b, c, 0, 0, 0)

// ---- async global->LDS staging helpers (T3/T4 pattern) ----------------------
__device__ __forceinline__ void gl_lds16(const u16* g, u16* l) {
    __builtin_amdgcn_global_load_lds(
        (const __attribute__((address_space(1))) unsigned int*)(const void*)g,
        (__attribute__((address_space(3))) unsigned int*)(void*)l, 16, 0, 0);
}
// Stage one 128-col chunk (64KB) of a [768][256] bf16 matrix into LDS.
// LDS layout: linear [cic][granule], but the SOURCE granule is pre-swizzled
// (gs ^ (cic&7)) so that swizzled ds_read_b128 on the consumer side is
// bank-conflict-free (source perm == read perm, involution).
__device__ __forceinline__ void stage_chunk(const u16* __restrict__ W, u16* buf,
                                            int c, int w, int lane) {
#pragma unroll
    for (int r = 0; r < 8; ++r) {
        int gran = (w * 8 + r) * 64 + lane;       // 16B granule index in chunk
        int cic = gran >> 5, gs = gran & 31;
        const u16* src = W + ((size_t)(c * 128 + cic) << 8) + ((gs ^ (cic & 7)) << 3);
        gl_lds16(src, buf + ((w * 8 + r) << 9));  // wave-uniform LDS base
    }
}
__device__ __forceinline__ void wait_vm8()   { asm volatile("s_waitcnt vmcnt(8)" ::: "memory"); }
__device__ __forceinline__ void wait_vm0()   { asm volatile("s_waitcnt vmcnt(0)" ::: "memory"); }
__device__ __forceinline__ void wait_lgkm0() { asm volatile("s_waitcnt lgkmcnt(0)" ::: "memory"); }
__device__ __forceinline__ void bar() {
    asm volatile("" ::: "memory");
    __builtin_amdgcn_s_barrier();
    asm volatile("" ::: "memory");
}

// ---------------------------------------------------------------------------
// Merged fp32 -> bf16 weight/activation casts (one launch)
// ---------------------------------------------------------------------------
__global__ __launch_bounds__(256) void k_prep(
    const float* __restrict__ gwhh_f, const float* __restrict__ gwhh_b,
    const float* __restrict__ cwhh,  const float* __restrict__ mw1,
    const float* __restrict__ mw2,   const float* __restrict__ condition,
    const float* __restrict__ cwih,
    u16* __restrict__ whhbf_f, u16* __restrict__ whhbf_b, u16* __restrict__ cwhhbf,
    u16* __restrict__ mw1bf, u16* __restrict__ mw2bf, u16* __restrict__ condbf,
    u16* __restrict__ cwcbf)
{
    long i = (long)blockIdx.x * 256 + threadIdx.x;
    if (i < 196608) { whhbf_f[i] = f2bf(gwhh_f[i]); return; } i -= 196608;
    if (i < 196608) { whhbf_b[i] = f2bf(gwhh_b[i]); return; } i -= 196608;
    if (i < 196608) { cwhhbf[i]  = f2bf(cwhh[i]);  return; } i -= 196608;
    if (i < 65536)  { mw1bf[i]   = f2bf(mw1[i]);   return; } i -= 65536;
    if (i < 65536)  { mw2bf[i]   = f2bf(mw2[i]);   return; } i -= 65536;
    if (i < 524288) { condbf[i]  = f2bf(condition[i]); return; } i -= 524288;
    if (i < 49152)  { long r = i >> 6, c = i & 63; cwcbf[i] = f2bf(cwih[r * 320 + c]); }
}

// ---------------------------------------------------------------------------
// Per-token input projections (bf16 tables, biases folded in)
// ---------------------------------------------------------------------------
__global__ __launch_bounds__(256) void k_tok_gi(
    const float* __restrict__ embed,
    const float* __restrict__ gwih_f, const float* __restrict__ gbih_f,
    const float* __restrict__ gwih_b, const float* __restrict__ gbih_b,
    const float* __restrict__ cwih,   const float* __restrict__ cbih,
    u16* __restrict__ gif, u16* __restrict__ gib, u16* __restrict__ gic)
{
    int v = blockIdx.x, tid = threadIdx.x;
    __shared__ float es[256];
    es[tid] = embed[v * HH + tid];
    __syncthreads();
    for (int g = 0; g < 3; ++g) {
        int col = g * 256 + tid;
        float af = gbih_f[col], abv = gbih_b[col], ac = cbih[col];
        const float* wf = gwih_f + (size_t)col * HH;
        const float* wb = gwih_b + (size_t)col * HH;
        const float* wc = cwih   + (size_t)col * (HH + CONDD) + CONDD;
        for (int c = 0; c < 256; ++c) {
            float e = es[c];
            af += e * wf[c]; abv += e * wb[c]; ac += e * wc[c];
        }
        gif[v * H3 + col] = f2bf(af);
        gib[v * H3 + col] = f2bf(abv);
        gic[v * H3 + col] = f2bf(ac);
    }
}

// ---------------------------------------------------------------------------
// w-trajectory + out[.,.,0..2] + tok_used (kills the w->lines->gic chain)
// ---------------------------------------------------------------------------
__global__ void k_wtraj(const int* __restrict__ actions, const int* __restrict__ w0,
                        const int* __restrict__ lines,
                        float* __restrict__ out, int* __restrict__ w_used,
                        int* __restrict__ tok_used)
{
    int n = threadIdx.x;
    int w = w0[n];
    for (int t = 0; t < TT; ++t) {
        int A = actions[((size_t)t * NN + n) * 2 + 0];
        int W = actions[((size_t)t * NN + n) * 2 + 1];
        w_used[t * NN + n] = w;
        tok_used[t * NN + n] = lines[n * NLL + w];
        int wn = w + W - NLL;
        wn = wn < 0 ? 0 : (wn > NLL - 1 ? NLL - 1 : wn);
        float* o = out + ((size_t)t * NN + n) * OW;
        o[0] = (float)A; o[1] = (float)W; o[2] = (float)wn;
        w = wn;
    }
}

// ---------------------------------------------------------------------------
// GRU: 256 blocks (1/CU), 512 thr, 32 rows/block, 16 steps.
// whh streamed via double-buffered global_load_lds, counted vmcnt(8),
// raw barriers; B-frag ds_read_b128 XOR-swizzled (conflict-free).
// MFMA conv (R4-verified): A lane holds h[m=lm][k=ks*32+lg*8+e];
// B lane holds W[col][same k]; C: col=lane&15, row=(lane>>4)*4+reg.
// Wave w owns cols {c*128 + w*16 + lm : c=0..5}; acc[c] -> gate via
// q = c>>1, cc = (c&1)*128 + w*16 + lm.
// ---------------------------------------------------------------------------
__global__ __launch_bounds__(512) void k_gru(
    const u16* __restrict__ whhbf_f, const u16* __restrict__ whhbf_b,
    const u16* __restrict__ gif, const u16* __restrict__ gib,
    const float* __restrict__ gbhh_f, const float* __restrict__ gbhh_b,
    const float* __restrict__ w2, const float* __restrict__ b2,
    float* __restrict__ Bf, float* __restrict__ Bb,
    const int* __restrict__ lines)
{
    __shared__ __align__(16) u16 hbf[32 * 264];        // 16.9 KB
    __shared__ __align__(16) u16 wbuf[2][32768];       // 128 KB (2 x 64KB chunks)
    __shared__ float w2s[8 * 256];                     // 8 KB
    __shared__ int   lns[32 * 16];                     // 2 KB

    const int tid = threadIdx.x, lane = tid & 63, w = tid >> 6;
    const int lm = lane & 15, lg = lane >> 4;
    const int bid = blockIdx.x, dir = bid >> 7, lb = bid & 127;
    const int ii = lb >> 3, nb = (lb & 7) * 32;
    const u16*   whh  = dir ? whhbf_b : whhbf_f;
    const u16*   git  = dir ? gib : gif;
    const float* bhh  = dir ? gbhh_b : gbhh_f;
    float*       Bout = dir ? Bb : Bf;

    const int cicw = w * 16 + lm;          // this thread's column-in-chunk
    const int cc0 = cicw, cc1 = cicw + 128;
    const float b_r[2] = { bhh[cc0],       bhh[cc1] };
    const float b_z[2] = { bhh[cc0 + 256], bhh[cc1 + 256] };
    const float b_n[2] = { bhh[cc0 + 512], bhh[cc1 + 512] };
    const float b2e = b2[tid & 7];

    for (int k = tid; k < 32 * 264; k += 512) hbf[k] = 0;
    for (int k = tid; k < 2048; k += 512) w2s[k] = w2[k];
    lns[tid & 511] = lines[(nb + (tid >> 4)) * NLL + (tid & 15)];
    __syncthreads();

    stage_chunk(whh, wbuf[0], 0, w, lane);             // prologue: chunk 0

    for (int s = 0; s < 16; ++s) {
        const int jpos = dir ? (15 - s) : s;
        const int jt = (ii + jpos) & 15;

        // A-fragments for this step (rows lm and 16+lm)
        bf16x8 a[2][8];
        #pragma unroll
        for (int ks = 0; ks < 8; ++ks) {
            a[0][ks] = *(const bf16x8*)&hbf[lm * 264 + ks * 32 + lg * 8];
            a[1][ks] = *(const bf16x8*)&hbf[(16 + lm) * 264 + ks * 32 + lg * 8];
        }
        f32x4 acc[6][2];
        #pragma unroll
        for (int c = 0; c < 6; ++c)
            #pragma unroll
            for (int rf = 0; rf < 2; ++rf)
                #pragma unroll
                for (int z = 0; z < 4; ++z) acc[c][rf][z] = 0.f;

        #pragma unroll
        for (int c = 0; c < 6; ++c) {
            if (s == 15 && c == 5) { wait_vm0(); }
            else { stage_chunk(whh, wbuf[(c + 1) & 1], (c + 1) % 6, w, lane); wait_vm8(); }
            bar();
            const u16* wb = wbuf[c & 1];
            #pragma unroll
            for (int ks = 0; ks < 8; ++ks) {
                bf16x8 b = *(const bf16x8*)&wb[(size_t)cicw * 256 + (((ks * 4 + lg) ^ (lm & 7)) << 3)];
                acc[c][0] = MFMA(a[0][ks], b, acc[c][0]);
                acc[c][1] = MFMA(a[1][ks], b, acc[c][1]);
            }
            bar();
        }

        // gate phase
        float hnew[2][2][4];
        #pragma unroll
        for (int half = 0; half < 2; ++half) {
            const int cc = half ? cc1 : cc0;
            #pragma unroll
            for (int rf = 0; rf < 2; ++rf)
                #pragma unroll
                for (int j = 0; j < 4; ++j) {
                    int lrow = rf * 16 + lg * 4 + j;
                    int tok  = lns[lrow * 16 + jt];
                    const u16* gi = git + (size_t)tok * H3;
                    float ho = bf2f(hbf[lrow * 264 + cc]);
                    float rg = sigm(bf2f(gi[cc])       + acc[half][rf][j]     + b_r[half]);
                    float zg = sigm(bf2f(gi[cc + 256]) + acc[2 + half][rf][j] + b_z[half]);
                    float ng = tanhfast(bf2f(gi[cc + 512]) + rg * (acc[4 + half][rf][j] + b_n[half]));
                    hnew[half][rf][j] = (1.f - zg) * ng + zg * ho;
                }
        }
        #pragma unroll
        for (int half = 0; half < 2; ++half) {
            const int cc = half ? cc1 : cc0;
            #pragma unroll
            for (int rf = 0; rf < 2; ++rf)
                #pragma unroll
                for (int j = 0; j < 4; ++j)
                    hbf[(rf * 16 + lg * 4 + j) * 264 + cc] = f2bf(hnew[half][rf][j]);
        }
        wait_lgkm0(); bar();                 // h visible block-wide

        // fused B projection (reads updated h, bf16)
        if (tid < 256) {
            int r = tid >> 3, e = tid & 7;
            float acb = b2e;
            for (int cx = 0; cx < 256; ++cx)
                acb += bf2f(hbf[r * 264 + cx]) * w2s[e * 256 + cx];
            int grow = ii * 256 + nb + r;
            Bout[((size_t)grow * NLL + jpos) * NEE + e] = sigm(acb);
        }
        // no barrier needed: hbf next written 12 barriers from now
    }
}

// ---------------------------------------------------------------------------
// Controller: 16 blocks x 512 thr, 16 rows/block, 32 steps.
// cwhh streamed (same pipeline); cond weights live in registers all steps.
// ---------------------------------------------------------------------------
__global__ __launch_bounds__(512) void k_ctrl(
    const u16* __restrict__ cwhhbf, const u16* __restrict__ cwcbf,
    const u16* __restrict__ condbf, const u16* __restrict__ gic,
    const float* __restrict__ cbhh, const float* __restrict__ h0,
    const int* __restrict__ tok_used,
    u16* __restrict__ Hallbf, float* __restrict__ out)
{
    __shared__ __align__(16) u16 hc[16 * 264];         // 8.4 KB
    __shared__ __align__(16) u16 wbuf[2][32768];       // 128 KB
    __shared__ int toks[16];

    const int tid = threadIdx.x, lane = tid & 63, w = tid >> 6;
    const int lm = lane & 15, lg = lane >> 4;
    const int cb = blockIdx.x;
    const int cicw = w * 16 + lm;
    const int cc0 = cicw, cc1 = cicw + 128;

    // cond-part weights in registers for the whole scan (12 frags = 48 VGPR)
    bf16x8 wc[6][2];
    #pragma unroll
    for (int c = 0; c < 6; ++c)
        #pragma unroll
        for (int k2 = 0; k2 < 2; ++k2)
            wc[c][k2] = *(const bf16x8*)&cwcbf[(size_t)(c * 128 + cicw) * 64 + k2 * 32 + lg * 8];

    const float cb_r[2] = { cbhh[cc0],       cbhh[cc1] };
    const float cb_z[2] = { cbhh[cc0 + 256], cbhh[cc1 + 256] };
    const float cb_n[2] = { cbhh[cc0 + 512], cbhh[cc1 + 512] };

    if (tid < 256) {
        int lrow = tid >> 4, c0 = (tid & 15) * 16;
        u16 tmp[16];
        #pragma unroll
        for (int k = 0; k < 16; ++k)
            tmp[k] = f2bf(h0[(size_t)(cb * 16 + lrow) * HH + c0 + k]);
        *(uint4*)&hc[lrow * 264 + c0]     = *(uint4*)&tmp[0];
        *(uint4*)&hc[lrow * 264 + c0 + 8] = *(uint4*)&tmp[8];
    }
    __syncthreads();

    stage_chunk(cwhhbf, wbuf[0], 0, w, lane);          // prologue

    for (int t = 0; t < TT; ++t) {
        if (tid < 16) toks[tid] = tok_used[t * NN + cb * 16 + tid];

        bf16x8 a[8];
        #pragma unroll
        for (int ks = 0; ks < 8; ++ks)
            a[ks] = *(const bf16x8*)&hc[lm * 264 + ks * 32 + lg * 8];
        bf16x8 ca[2];
        #pragma unroll
        for (int k2 = 0; k2 < 2; ++k2)
            ca[k2] = *(const bf16x8*)&condbf[(size_t)(t * NN + cb * 16 + lm) * 64 + k2 * 32 + lg * 8];

        f32x4 acc[6], accC[2];
        #pragma unroll
        for (int c = 0; c < 6; ++c)
            #pragma unroll
            for (int z = 0; z < 4; ++z) acc[c][z] = 0.f;
        #pragma unroll
        for (int c = 0; c < 2; ++c)
            #pragma unroll
            for (int z = 0; z < 4; ++z) accC[c][z] = 0.f;

        // cond GEMM (pure-register, overlaps chunk-0 staging latency)
        #pragma unroll
        for (int c = 0; c < 6; ++c)
            #pragma unroll
            for (int k2 = 0; k2 < 2; ++k2) {
                if (c < 4) acc[c]      = MFMA(ca[k2], wc[c][k2], acc[c]);
                else       accC[c - 4] = MFMA(ca[k2], wc[c][k2], accC[c - 4]);
            }

        #pragma unroll
        for (int c = 0; c < 6; ++c) {
            if (t == 31 && c == 5) { wait_vm0(); }
            else { stage_chunk(cwhhbf, wbuf[(c + 1) & 1], (c + 1) % 6, w, lane); wait_vm8(); }
            bar();
            const u16* wb = wbuf[c & 1];
            #pragma unroll
            for (int ks = 0; ks < 8; ++ks) {
                bf16x8 b = *(const bf16x8*)&wb[(size_t)cicw * 256 + (((ks * 4 + lg) ^ (lm & 7)) << 3)];
                acc[c] = MFMA(a[ks], b, acc[c]);
            }
            bar();
        }

        // gate + outputs
        float hn2[2][4];
        #pragma unroll
        for (int half = 0; half < 2; ++half) {
            const int cc = half ? cc1 : cc0;
            #pragma unroll
            for (int j = 0; j < 4; ++j) {
                int lrow = lg * 4 + j;
                int n = cb * 16 + lrow;
                int tok = toks[lrow];
                const u16* gi = gic + (size_t)tok * H3;
                float ho = bf2f(hc[lrow * 264 + cc]);
                float rg = sigm(bf2f(gi[cc])       + acc[half][j]     + cb_r[half]);
                float zg = sigm(bf2f(gi[cc + 256]) + acc[2 + half][j] + cb_z[half]);
                float ng = tanhfast(bf2f(gi[cc + 512]) + accC[half][j]
                                    + rg * (acc[4 + half][j] + cb_n[half]));
                float hn = (1.f - zg) * ng + zg * ho;
                out[((size_t)t * NN + n) * OW + 4 + cc] = hn;
                Hallbf[((size_t)t * NN + n) * HH + cc] = f2bf(hn);
                hn2[half][j] = hn;
            }
        }
        #pragma unroll
        for (int half = 0; half < 2; ++half) {
            const int cc = half ? cc1 : cc0;
            #pragma unroll
            for (int j = 0; j < 4; ++j)
                hc[(lg * 4 + j) * 264 + cc] = f2bf(hn2[half][j]);
        }
        wait_lgkm0(); bar();
    }
}

// ---------------------------------------------------------------------------
// Stick-breaking + reversals + roll into final P layout (verified)
// ---------------------------------------------------------------------------
__global__ __launch_bounds__(256) void k_stick(
    const float* __restrict__ Bf, const float* __restrict__ Bb,
    float* __restrict__ P_final)
{
    int idx = blockIdx.x * 256 + threadIdx.x;
    if (idx >= 16 * 256 * 8) return;
    int e = idx & 7, n = (idx >> 3) & 255, i = idx >> 11;
    const float* bf = Bf + ((size_t)(i * NN + n) * NLL) * NEE + e;
    const float* bb = Bb + ((size_t)(i * NN + n) * NLL) * NEE + e;
    int i2 = (i + 15) & 15;
    float* dst = P_final + ((size_t)(i2 * NN + n) * 32) * NEE + e;
    float cum = 1.f;
    #pragma unroll
    for (int m = 0; m < 16; ++m) {
        float c0 = bf[m * NEE];
        float c1 = bb[(15 - m) * NEE];
        float v0 = c0 * cum;
        cum *= (1.f - c0);
        float v1 = (m < 15) ? c1 * cum : cum;
        cum *= (1.f - c1);
        dst[(size_t)(((17 + m) & 31)) * NEE] = v0;
        dst[(size_t)((16 - m)) * NEE]        = v1;
    }
}

// ---------------------------------------------------------------------------
// Batched MLP layer: Out = bf16(relu(A @ W^T + bias)), A (8192,256) bf16
// ---------------------------------------------------------------------------
__global__ __launch_bounds__(256) void k_mlp(
    const u16* __restrict__ A, const u16* __restrict__ W,
    const float* __restrict__ bias, u16* __restrict__ Out)
{
    __shared__ u16 ot[32 * 264];
    const int g0 = blockIdx.x * 32;
    const int tid = threadIdx.x, lane = tid & 63, w = tid >> 6;
    const int lm = lane & 15, lg = lane >> 4;
    f32x4 acc[4][2];
    #pragma unroll
    for (int c = 0; c < 4; ++c)
        #pragma unroll
        for (int r = 0; r < 2; ++r)
            #pragma unroll
            for (int z = 0; z < 4; ++z) acc[c][r][z] = 0.f;
    #pragma unroll
    for (int ks = 0; ks < 8; ++ks) {
        bf16x8 a0 = *(const bf16x8*)&A[(size_t)(g0 + lm) * 256 + ks * 32 + lg * 8];
        bf16x8 a1 = *(const bf16x8*)&A[(size_t)(g0 + 16 + lm) * 256 + ks * 32 + lg * 8];
        #pragma unroll
        for (int cf = 0; cf < 4; ++cf) {
            const u16* bp = W + (size_t)(w * 64 + cf * 16 + lm) * 256 + ks * 32 + lg * 8;
            bf16x8 b = *(const bf16x8*)bp;
            acc[cf][0] = MFMA(a0, b, acc[cf][0]);
            acc[cf][1] = MFMA(a1, b, acc[cf][1]);
        }
    }
    #pragma unroll
    for (int cf = 0; cf < 4; ++cf) {
        int col = w * 64 + cf * 16 + lm;
        float bs = bias[col];
        #pragma unroll
        for (int rf = 0; rf < 2; ++rf)
            #pragma unroll
            for (int j = 0; j < 4; ++j) {
                int lrow = rf * 16 + lg * 4 + j;
                ot[lrow * 264 + col] = f2bf(fmaxf(acc[cf][rf][j] + bs, 0.f));
            }
    }
    __syncthreads();
    int lrow = tid >> 3, c0 = (tid & 7) * 32;
    const uint4* src = (const uint4*)&ot[lrow * 264 + c0];
    uint4* dst = (uint4*)&Out[(size_t)(g0 + lrow) * 256 + c0];
    dst[0] = src[0]; dst[1] = src[1]; dst[2] = src[2]; dst[3] = src[3];
}

// ---------------------------------------------------------------------------
// Heads: 25 logits per row + softmaxes + v + p_probs
// ---------------------------------------------------------------------------
__global__ __launch_bounds__(256) void k_heads(
    const u16* __restrict__ zbf,
    const float* __restrict__ aw, const float* __restrict__ ab,
    const float* __restrict__ ow, const float* __restrict__ ob,
    const float* __restrict__ cw, const float* __restrict__ cb,
    const float* __restrict__ P_final, const int* __restrict__ w_used,
    float* __restrict__ out)
{
    __shared__ float zt[32 * 258];
    __shared__ float hd[32][28];
    __shared__ float o8[32][8];
    __shared__ int   wv[32];
    const int g0 = blockIdx.x * 32, tid = threadIdx.x;
    {
        int lrow = tid >> 3, c0 = (tid & 7) * 32;
        const u16* src = &zbf[(size_t)(g0 + lrow) * 256 + c0];
        #pragma unroll
        for (int k = 0; k < 32; ++k) zt[lrow * 258 + c0 + k] = bf2f(src[k]);
    }
    if (tid < 32) wv[tid] = w_used[g0 + tid];
    __syncthreads();
    {
        int r = tid >> 3, s = tid & 7;
        const float* z = &zt[r * 258];
        float a1 = ab[s], a2 = ab[8 + s], a3 = ob[s], a4 = cb[0];
        const float* w1 = aw + s * 256;
        const float* w2_ = aw + (8 + s) * 256;
        const float* w3 = ow + s * 256;
        for (int c = 0; c < 256; ++c) {
            float zv = z[c];
            a1 += zv * w1[c]; a2 += zv * w2_[c]; a3 += zv * w3[c]; a4 += zv * cw[c];
        }
        hd[r][s] = a1; hd[r][8 + s] = a2; hd[r][16 + s] = a3;
        if (s == 0) hd[r][24] = a4;
    }
    __syncthreads();
    if (tid < 32) {
        int r = tid; int g = g0 + r;
        float* orow = out + (size_t)g * OW;
        float mx = hd[r][0];
        #pragma unroll
        for (int k = 1; k < 16; ++k) mx = fmaxf(mx, hd[r][k]);
        float ex[16], ssum = 0.f;
        #pragma unroll
        for (int k = 0; k < 16; ++k) { ex[k] = __expf(hd[r][k] - mx); ssum += ex[k]; }
        float inv = 1.f / ssum;
        #pragma unroll
        for (int k = 0; k < 16; ++k) orow[260 + k] = ex[k] * inv;
        orow[3] = hd[r][24];
        float mo = hd[r][16];
        #pragma unroll
        for (int k = 1; k < 8; ++k) mo = fmaxf(mo, hd[r][16 + k]);
        float eo[8], so = 0.f;
        #pragma unroll
        for (int k = 0; k < 8; ++k) { eo[k] = __expf(hd[r][16 + k] - mo); so += eo[k]; }
        float invo = 1.f / so;
        #pragma unroll
        for (int k = 0; k < 8; ++k) o8[r][k] = eo[k] * invo;
    }
    __syncthreads();
    {
        int r = tid >> 3, kb = tid & 7;
        int g = g0 + r, n = g & 255;
        const float* base = P_final + ((size_t)(wv[r] * NN + n) * 32) * NEE;
        float* orow = out + (size_t)g * OW + 276;
        #pragma unroll
        for (int m = 0; m < 4; ++m) {
            int k = kb + m * 8;
            const float* pe = base + k * NEE;
            float a = 0.f;
            #pragma unroll
            for (int e = 0; e < 8; ++e) a += pe[e] * o8[r][e];
            orow[k] = a;
        }
    }
}

// ---------------------------------------------------------------------------
extern "C" void kernel_launch(void* const* d_in, const int* in_sizes, int n_in,
                              void* d_out, int out_size, void* d_ws, size_t ws_size,
                              hipStream_t stream) {
    const float* condition = (const float*)d_in[0];
    const int*   lines     = (const int*)  d_in[1];
    const int*   actions   = (const int*)  d_in[2];
    const float* h0        = (const float*)d_in[3];
    const int*   w0        = (const int*)  d_in[4];
    const float* embed     = (const float*)d_in[5];
    const float* gwih_f    = (const float*)d_in[6];
    const float* gwhh_f    = (const float*)d_in[7];
    const float* gbih_f    = (const float*)d_in[8];
    const float* gbhh_f    = (const float*)d_in[9];
    const float* gwih_b    = (const float*)d_in[10];
    const float* gwhh_b    = (const float*)d_in[11];
    const float* gbih_b    = (const float*)d_in[12];
    const float* gbhh_b    = (const float*)d_in[13];
    const float* w2        = (const float*)d_in[14];
    const float* b2        = (const float*)d_in[15];
    const float* cwih      = (const float*)d_in[16];
    const float* cwhh      = (const float*)d_in[17];
    const float* cbih      = (const float*)d_in[18];
    const float* cbhh      = (const float*)d_in[19];
    const float* mw1       = (const float*)d_in[20];
    const float* mb1       = (const float*)d_in[21];
    const float* mw2       = (const float*)d_in[22];
    const float* mb2       = (const float*)d_in[23];
    const float* ow        = (const float*)d_in[24];
    const float* ob        = (const float*)d_in[25];
    const float* aw        = (const float*)d_in[26];
    const float* ab        = (const float*)d_in[27];
    const float* cw        = (const float*)d_in[28];
    const float* cb        = (const float*)d_in[29];
    float* out = (float*)d_out;

    // workspace carve-up (~18 MB)
    char* base = (char*)d_ws;
    auto alloc = [&](size_t bytes) { char* r = base; base += (bytes + 255) & ~(size_t)255; return r; };
    u16*   gif_tok = (u16*)alloc(64 * H3 * 2);
    u16*   gib_tok = (u16*)alloc(64 * H3 * 2);
    u16*   gic_tok = (u16*)alloc(64 * H3 * 2);
    u16*   whhbf_f = (u16*)alloc(H3 * 256 * 2);
    u16*   whhbf_b = (u16*)alloc(H3 * 256 * 2);
    u16*   cwhhbf  = (u16*)alloc(H3 * 256 * 2);
    u16*   mw1bf   = (u16*)alloc(256 * 256 * 2);
    u16*   mw2bf   = (u16*)alloc(256 * 256 * 2);
    u16*   cwcbf   = (u16*)alloc(H3 * 64 * 2);
    u16*   condbf  = (u16*)alloc((size_t)TT * NN * CONDD * 2);
    float* Bf      = (float*)alloc((size_t)16 * 256 * 16 * 8 * 4);   // aliased: z1bf
    float* Bb      = (float*)alloc((size_t)16 * 256 * 16 * 8 * 4);
    float* P_final = (float*)alloc((size_t)16 * 256 * 32 * 8 * 4);
    u16*   Hallbf  = (u16*)alloc((size_t)TT * NN * 256 * 2);
    u16*   zbf     = (u16*)alloc((size_t)TT * NN * 256 * 2);
    int*   w_used  = (int*)alloc((size_t)TT * NN * 4);
    int*   tok_used= (int*)alloc((size_t)TT * NN * 4);
    u16*   z1bf    = (u16*)Bf;   // reuse Bf+Bb after k_stick

    k_prep<<<5056, 256, 0, stream>>>(gwhh_f, gwhh_b, cwhh, mw1, mw2, condition, cwih,
                                     whhbf_f, whhbf_b, cwhhbf, mw1bf, mw2bf, condbf, cwcbf);

    k_tok_gi<<<64, 256, 0, stream>>>(embed, gwih_f, gbih_f, gwih_b, gbih_b, cwih, cbih,
                                     gif_tok, gib_tok, gic_tok);
    k_wtraj<<<1, 256, 0, stream>>>(actions, w0, lines, out, w_used, tok_used);

    k_gru<<<256, 512, 0, stream>>>(whhbf_f, whhbf_b, gif_tok, gib_tok, gbhh_f, gbhh_b,
                                   w2, b2, Bf, Bb, lines);

    k_ctrl<<<16, 512, 0, stream>>>(cwhhbf, cwcbf, condbf, gic_tok, cbhh, h0, tok_used,
                                   Hallbf, out);

    k_stick<<<128, 256, 0, stream>>>(Bf, Bb, P_final);

    k_mlp<<<256, 256, 0, stream>>>(Hallbf, mw1bf, mb1, z1bf);
    k_mlp<<<256, 256, 0, stream>>>(z1bf, mw2bf, mb2, zbf);

    k_heads<<<256, 256, 0, stream>>>(zbf, aw, ab, ow, ob, cw, cb, P_final, w_used, out);
}